// Round 4
// baseline (136.607 us; speedup 1.0000x reference)
//
#include <hip/hip_runtime.h>

#define S 128
#define NPLANES 1024                  // B*C
#define NTHREADS (NPLANES * S * (S / 4))   // 4,194,304 (one float4 of one row each)
#define NBLOCKS (NTHREADS / 256)           // 16384

__global__ __launch_bounds__(256, 8) void pairwise_potential_kernel(
    const float* __restrict__ x, const float* __restrict__ w1,
    const float* __restrict__ w2, float* __restrict__ out)
{
    const int t     = blockIdx.x * 256 + threadIdx.x;
    const int seg   = t & 31;           // which float4 within the row
    const int row   = (t >> 5) & (S - 1);
    const int plane = t >> 12;          // b*64 + c
    const int c     = plane & 63;
    const int col   = seg << 2;

    const float* xp = x + ((size_t)plane << 14);
    const int rm = max(row - 1, 0);
    const int rp = min(row + 1, S - 1);
    const float* pm = xp + rm  * S + col;
    const float* p0 = xp + row * S + col;
    const float* pp = xp + rp  * S + col;

    // ---- 11 independent loads, straight-line ----
    float4 va = *reinterpret_cast<const float4*>(pm);
    float4 vb = *reinterpret_cast<const float4*>(p0);
    float4 vc = *reinterpret_cast<const float4*>(pp);
    const int lo = (seg == 0)  ? 0 : -1;   // clamped halo offsets
    const int ho = (seg == 31) ? 3 :  4;
    float la = pm[lo], lb = p0[lo], lc = pp[lo];
    float ha = pm[ho], hb = p0[ho], hc = pp[ho];

    const float* wbase1 = w1 + (size_t)c * (S * S) + row * S + col;
    const float* wbase2 = w2 + (size_t)c * (S * S) + row * S + col;
    const float4 w1v = *reinterpret_cast<const float4*>(wbase1);
    const float4 w2v = *reinterpret_cast<const float4*>(wbase2);

    // ---- zero-pad masking (branchless) ----
    if (seg == 0)  { la = 0.f; lb = 0.f; lc = 0.f; }
    if (seg == 31) { ha = 0.f; hb = 0.f; hc = 0.f; }
    const float mt = (row == 0)     ? 0.f : 1.f;
    const float mb = (row == S - 1) ? 0.f : 1.f;
    va.x *= mt; va.y *= mt; va.z *= mt; va.w *= mt; la *= mt; ha *= mt;
    vc.x *= mb; vc.y *= mb; vc.z *= mb; vc.w *= mb; lc *= mb; hc *= mb;

    float m0[6] = { la, va.x, va.y, va.z, va.w, ha };
    float m1[6] = { lb, vb.x, vb.y, vb.z, vb.w, hb };
    float m2[6] = { lc, vc.x, vc.y, vc.z, vc.w, hc };

    const float NL  = -0.72134752044f;    // -0.5 * log2(e)
    const float E1N = 0.06739229552f;     // exp(-0.5)/9        (d = 1)
    const float E2N = 0.05478541015f;     // exp(-sqrt2/2)/9    (d = sqrt2)
    const float C9  = 0.11111111111f;     // exp(0)/9           (center term)
    const float W2C = 1.07298380550f;     // (4 + 4*sqrt(2)) / 9

    const float* w1a = &w1v.x;
    const float* w2a = &w2v.x;
    float4 o;
    float* ov = &o.x;
    #pragma unroll
    for (int k = 0; k < 4; ++k) {
        const float cen = m0[k];          // X(h-1, w-1): window root
        float d;
        d = cen - m0[k + 1]; const float a0 = __builtin_amdgcn_exp2f(d * d * NL);
        d = cen - m0[k + 2]; const float a1 = __builtin_amdgcn_exp2f(d * d * NL);
        d = cen - m1[k];     const float a2 = __builtin_amdgcn_exp2f(d * d * NL);
        d = cen - m2[k];     const float a3 = __builtin_amdgcn_exp2f(d * d * NL);
        d = cen - m1[k + 1]; const float b0 = __builtin_amdgcn_exp2f(d * d * NL);
        d = cen - m1[k + 2]; const float b1 = __builtin_amdgcn_exp2f(d * d * NL);
        d = cen - m2[k + 1]; const float b2 = __builtin_amdgcn_exp2f(d * d * NL);
        d = cen - m2[k + 2]; const float b3 = __builtin_amdgcn_exp2f(d * d * NL);
        const float s1 = (a0 + a1) + (a2 + a3);
        const float s2 = (b0 + b1) + (b2 + b3);
        const float fN = fmaf(E2N, s2, fmaf(E1N, s1, C9));   // first/9
        ov[k] = fmaf(w1a[k], fN, w2a[k] * W2C);
    }
    float* op = out + ((size_t)plane << 14) + row * S + col;
    *reinterpret_cast<float4*>(op) = o;
}

extern "C" void kernel_launch(void* const* d_in, const int* in_sizes, int n_in,
                              void* d_out, int out_size, void* d_ws, size_t ws_size,
                              hipStream_t stream) {
    const float* x  = (const float*)d_in[0];
    const float* w1 = (const float*)d_in[1];
    const float* w2 = (const float*)d_in[2];
    float* out = (float*)d_out;
    pairwise_potential_kernel<<<NBLOCKS, 256, 0, stream>>>(x, w1, w2, out);
}

// Round 5
// 136.212 us; speedup vs baseline: 1.0029x; 1.0029x over previous
//
#include <hip/hip_runtime.h>

#define S 128
#define NPLANES 1024                  // B*C
#define NTHREADS (NPLANES * S * (S / 4))   // 4,194,304 (one float4 of one row each)
#define NBLOCKS (NTHREADS / 256)           // 16384

__global__ __launch_bounds__(256, 6) void pairwise_potential_kernel(
    const float* __restrict__ x, const float* __restrict__ w1,
    const float* __restrict__ w2, float* __restrict__ out)
{
    const int t     = blockIdx.x * 256 + threadIdx.x;
    const int seg   = t & 31;           // which float4 within the row
    const int row   = (t >> 5) & (S - 1);
    const int plane = t >> 12;          // b*64 + c
    const int c     = plane & 63;
    const int col   = seg << 2;

    const float* xp = x + ((size_t)plane << 14);
    const int rm = max(row - 1, 0);
    const int rp = min(row + 1, S - 1);
    const float* pm = xp + rm  * S + col;
    const float* p0 = xp + row * S + col;
    const float* pp = xp + rp  * S + col;
    const int lo = (seg == 0)  ? 0 : -1;   // clamped halo offsets
    const int ho = (seg == 31) ? 3 :  4;
    const float* wbase1 = w1 + (size_t)c * (S * S) + row * S + col;
    const float* wbase2 = w2 + (size_t)c * (S * S) + row * S + col;

    // ---- 11 independent loads, forced to issue as one burst ----
    float4 va = *reinterpret_cast<const float4*>(pm);
    float4 vb = *reinterpret_cast<const float4*>(p0);
    float4 vc = *reinterpret_cast<const float4*>(pp);
    float la = pm[lo], lb = p0[lo], lc = pp[lo];
    float ha = pm[ho], hb = p0[ho], hc = pp[ho];
    const float4 w1v = *reinterpret_cast<const float4*>(wbase1);
    const float4 w2v = *reinterpret_cast<const float4*>(wbase2);
    __builtin_amdgcn_sched_barrier(0);   // loads may NOT sink past this point

    // ---- zero-pad masking (branchless) ----
    if (seg == 0)  { la = 0.f; lb = 0.f; lc = 0.f; }
    if (seg == 31) { ha = 0.f; hb = 0.f; hc = 0.f; }
    const float mt = (row == 0)     ? 0.f : 1.f;
    const float mb = (row == S - 1) ? 0.f : 1.f;
    va.x *= mt; va.y *= mt; va.z *= mt; va.w *= mt; la *= mt; ha *= mt;
    vc.x *= mb; vc.y *= mb; vc.z *= mb; vc.w *= mb; lc *= mb; hc *= mb;

    float m0[6] = { la, va.x, va.y, va.z, va.w, ha };
    float m1[6] = { lb, vb.x, vb.y, vb.z, vb.w, hb };
    float m2[6] = { lc, vc.x, vc.y, vc.z, vc.w, hc };

    const float NL  = -0.72134752044f;    // -0.5 * log2(e)
    const float E1N = 0.06739229552f;     // exp(-0.5)/9        (d = 1)
    const float E2N = 0.05478541015f;     // exp(-sqrt2/2)/9    (d = sqrt2)
    const float C9  = 0.11111111111f;     // exp(0)/9           (center term)
    const float W2C = 1.07298380550f;     // (4 + 4*sqrt(2)) / 9

    const float* w1a = &w1v.x;
    const float* w2a = &w2v.x;
    float4 o;
    float* ov = &o.x;
    #pragma unroll
    for (int k = 0; k < 4; ++k) {
        const float cen = m0[k];          // X(h-1, w-1): window root
        float d;
        d = cen - m0[k + 1]; const float a0 = __builtin_amdgcn_exp2f(d * d * NL);
        d = cen - m0[k + 2]; const float a1 = __builtin_amdgcn_exp2f(d * d * NL);
        d = cen - m1[k];     const float a2 = __builtin_amdgcn_exp2f(d * d * NL);
        d = cen - m2[k];     const float a3 = __builtin_amdgcn_exp2f(d * d * NL);
        d = cen - m1[k + 1]; const float b0 = __builtin_amdgcn_exp2f(d * d * NL);
        d = cen - m1[k + 2]; const float b1 = __builtin_amdgcn_exp2f(d * d * NL);
        d = cen - m2[k + 1]; const float b2 = __builtin_amdgcn_exp2f(d * d * NL);
        d = cen - m2[k + 2]; const float b3 = __builtin_amdgcn_exp2f(d * d * NL);
        const float s1 = (a0 + a1) + (a2 + a3);
        const float s2 = (b0 + b1) + (b2 + b3);
        const float fN = fmaf(E2N, s2, fmaf(E1N, s1, C9));   // first/9
        ov[k] = fmaf(w1a[k], fN, w2a[k] * W2C);
    }
    float* op = out + ((size_t)plane << 14) + row * S + col;
    *reinterpret_cast<float4*>(op) = o;
}

extern "C" void kernel_launch(void* const* d_in, const int* in_sizes, int n_in,
                              void* d_out, int out_size, void* d_ws, size_t ws_size,
                              hipStream_t stream) {
    const float* x  = (const float*)d_in[0];
    const float* w1 = (const float*)d_in[1];
    const float* w2 = (const float*)d_in[2];
    float* out = (float*)d_out;
    pairwise_potential_kernel<<<NBLOCKS, 256, 0, stream>>>(x, w1, w2, out);
}

// Round 6
// 124.915 us; speedup vs baseline: 1.0936x; 1.0904x over previous
//
#include <hip/hip_runtime.h>

#define S 128
#define ROWS 32                          // output rows per block
#define NPLANES 1024                     // B*C
#define NBLOCKS (NPLANES * (S / ROWS))   // 4096 blocks x 256 threads

typedef const __attribute__((address_space(1))) void* gas_t;
typedef __attribute__((address_space(3))) void* las_t;

__global__ __launch_bounds__(256, 4) void pairwise_potential_kernel(
    const float* __restrict__ x, const float* __restrict__ w1,
    const float* __restrict__ w2, float* __restrict__ out)
{
    __shared__ float tile[(ROWS + 2) * S];   // 34 x 128 floats = 17408 B

    const int tid = threadIdx.x;
    const int l   = tid & 63;      // lane in wave
    const int wid = tid >> 6;      // wave id 0..3
    const int qc  = tid & 31;      // quad-column 0..31
    const int rg  = tid >> 5;      // row group 0..7 (4 rows each)

    const int plane = blockIdx.x >> 2;       // b*64 + c
    const int band  = blockIdx.x & 3;
    const int r0    = band * ROWS;
    const int c     = plane & 63;

    const float* xp = x + ((size_t)plane << 14);
    const int col   = qc * 4;
    const int rbase = r0 + rg * 4;

    // ---- w1/w2 register loads (drained by the staging barrier) ----
    const float* w1p = w1 + (size_t)c * (S * S);
    const float* w2p = w2 + (size_t)c * (S * S);
    float4 w1v[4], w2v[4];
    #pragma unroll
    for (int q = 0; q < 4; ++q) {
        w1v[q] = *(const float4*)(w1p + (rbase + q) * S + col);
        w2v[q] = *(const float4*)(w2p + (rbase + q) * S + col);
    }

    // ---- stage x tile into LDS, no VGPR round-trip ----
    // core: 16 chunks of 1 KB = 2 rows each; chunk i -> tile rows 1+2i..2+2i  (x rows r0+2i..r0+2i+1)
    #pragma unroll
    for (int j = 0; j < 4; ++j) {
        const int i = wid * 4 + j;
        const float* src = xp + (r0 + 2 * i) * S + l * 4;
        __builtin_amdgcn_global_load_lds((gas_t)src, (las_t)&tile[(1 + 2 * i) * S], 16, 0, 0);
    }
    // halo rows (clamped source; masked at compute for plane edges):
    //   tile row 0  = x row max(r0-1,0);  tile row 33 = x row min(r0+32,127)
    {
        const int hr   = (wid < 2) ? max(r0 - 1, 0) : min(r0 + ROWS, S - 1);
        const int trr  = (wid < 2) ? 0 : ROWS + 1;
        const int half = (wid & 1) * 64;          // two 256B halves per row
        const float* src = xp + hr * S + half + l;
        __builtin_amdgcn_global_load_lds((gas_t)src, (las_t)&tile[trr * S + half], 4, 0, 0);
    }
    __syncthreads();

    // ---- read the 6 window rows (LDS + shfl halo) ----
    float m[6][6];    // [winrow][0..5] = [left | q0 q1 q2 q3 | right]
    #pragma unroll
    for (int j = 0; j < 6; ++j) {
        const int tr = rg * 4 + j;               // tile row = x row rbase-1+j
        const float4 v = *(const float4*)&tile[tr * S + col];
        float lf = __shfl(v.w, (l - 1) & 63, 64);
        float rf = __shfl(v.x, (l + 1) & 63, 64);
        if (qc == 0)  lf = 0.f;                  // col -1  zero-pad (also kills cross-half shfl)
        if (qc == 31) rf = 0.f;                  // col 128 zero-pad
        m[j][0] = lf; m[j][1] = v.x; m[j][2] = v.y; m[j][3] = v.z; m[j][4] = v.w; m[j][5] = rf;
    }
    // vertical zero-pad: x row -1 (only thread rows starting at 0), x row 128
    if (rbase == 0) {
        #pragma unroll
        for (int t = 0; t < 6; ++t) m[0][t] = 0.f;
    }
    if (rbase + 4 == S) {
        #pragma unroll
        for (int t = 0; t < 6; ++t) m[5][t] = 0.f;
    }

    const float NL  = -0.72134752044f;    // -0.5 * log2(e)
    const float E1N = 0.06739229552f;     // exp(-0.5)/9        (d = 1)
    const float E2N = 0.05478541015f;     // exp(-sqrt2/2)/9    (d = sqrt2)
    const float C9  = 0.11111111111f;     // exp(0)/9           (center term)
    const float W2C = 1.07298380550f;     // (4 + 4*sqrt(2)) / 9

    float* op = out + ((size_t)plane << 14) + rbase * S + col;
    #pragma unroll
    for (int q = 0; q < 4; ++q) {
        const float* m0 = m[q];
        const float* m1 = m[q + 1];
        const float* m2 = m[q + 2];
        const float* w1a = &w1v[q].x;
        const float* w2a = &w2v[q].x;
        float4 o;
        float* ov = &o.x;
        #pragma unroll
        for (int k = 0; k < 4; ++k) {
            const float cen = m0[k];      // X(h-1, w-1): window root
            float d;
            d = cen - m0[k + 1]; const float a0 = __builtin_amdgcn_exp2f(d * d * NL);
            d = cen - m0[k + 2]; const float a1 = __builtin_amdgcn_exp2f(d * d * NL);
            d = cen - m1[k];     const float a2 = __builtin_amdgcn_exp2f(d * d * NL);
            d = cen - m2[k];     const float a3 = __builtin_amdgcn_exp2f(d * d * NL);
            d = cen - m1[k + 1]; const float b0 = __builtin_amdgcn_exp2f(d * d * NL);
            d = cen - m1[k + 2]; const float b1 = __builtin_amdgcn_exp2f(d * d * NL);
            d = cen - m2[k + 1]; const float b2 = __builtin_amdgcn_exp2f(d * d * NL);
            d = cen - m2[k + 2]; const float b3 = __builtin_amdgcn_exp2f(d * d * NL);
            const float s1 = (a0 + a1) + (a2 + a3);
            const float s2 = (b0 + b1) + (b2 + b3);
            const float fN = fmaf(E2N, s2, fmaf(E1N, s1, C9));   // first/9
            ov[k] = fmaf(w1a[k], fN, w2a[k] * W2C);
        }
        *reinterpret_cast<float4*>(op + q * S) = o;
    }
}

extern "C" void kernel_launch(void* const* d_in, const int* in_sizes, int n_in,
                              void* d_out, int out_size, void* d_ws, size_t ws_size,
                              hipStream_t stream) {
    const float* x  = (const float*)d_in[0];
    const float* w1 = (const float*)d_in[1];
    const float* w2 = (const float*)d_in[2];
    float* out = (float*)d_out;
    pairwise_potential_kernel<<<NBLOCKS, 256, 0, stream>>>(x, w1, w2, out);
}